// Round 7
// baseline (12974.472 us; speedup 1.0000x reference)
//
#include <hip/hip_runtime.h>

typedef unsigned short ushort_t;
typedef __attribute__((ext_vector_type(8))) short short8;
typedef __attribute__((ext_vector_type(4))) float f32x4;

#define HH 64
#define TT 12
#define TOUT 12
#define CC 10
#define BNTOT 131072

// bf16 hi/lo split helpers (truncation; 3-term product error ~2^-16 rel)
__device__ __forceinline__ ushort_t hib(float f){ return (ushort_t)(__float_as_uint(f) >> 16); }
__device__ __forceinline__ float ubf(ushort_t u){ return __uint_as_float(((unsigned)u) << 16); }
__device__ __forceinline__ ushort_t lob(float f){ float r = f - ubf(hib(f)); return hib(r); }

__device__ __forceinline__ float sigm(float x){
  return __builtin_amdgcn_rcpf(1.0f + __expf(-x));
}
__device__ __forceinline__ float tanh_f(float x){
  return 1.0f - 2.0f * __builtin_amdgcn_rcpf(1.0f + __expf(2.0f * x));
}

struct W {
  const float* ewih; const float* ewhh; const float* ebih; const float* ebhh;
  const float* dwih; const float* dwhh; const float* dbih; const float* dbhh;
  const float* l1w;  const float* l1b;  const float* l2w;  const float* l2b;
  const float* emb;
};

// ===================== prep: ONLY the enc-hv (g16) tiles now =====================
// tile id s = c*4 + kt*2 + term; element e: L=e>>3, jj=e&7, col=L&15, kk=(L>>4)*8+jj
// B[k=2t+f'][col]: kt=0 -> col=2s_+f_ (s_<8); kt=1 -> col=2(s_-8)+f_ (cols 0..7).
// rows kk=24/25 = b2 hi/lo (term0 only; A carries exact 1.0 there).
__global__ void prep_hv(W w, ushort_t* __restrict__ fb){
  const int s = blockIdx.x;           // 40 blocks
  const int term = s & 1, kt = (s >> 1) & 1, c = s >> 2;
  #pragma unroll
  for (int u = 0; u < 2; ++u){
    const int e = threadIdx.x*2 + u;
    const int L = e >> 3, jj = e & 7;
    const int col = L & 15, kk = (L >> 4)*8 + jj;
    ushort_t r = 0;
    int s_, f_, ok = 1;
    if (kt == 0){ s_ = col >> 1; f_ = col & 1; }
    else { if (col >= 8) ok = 0; s_ = 8 + (col >> 1); f_ = col & 1; }
    if (ok){
      if (kk < 24){
        const int t = kk >> 1, f2 = kk & 1;
        const float v = (f2 == f_) ? w.l2w[c*144 + s_*12 + t] : 0.f;
        r = term ? lob(v) : hib(v);
      } else if (kk == 24){ r = term ? (ushort_t)0 : hib(w.l2b[c*12 + s_]); }
      else if (kk == 25){ r = term ? (ushort_t)0 : lob(w.l2b[c*12 + s_]); }
    }
    fb[(size_t)s*512 + e] = r;
  }
}

// ===================== main kernel =====================
#define MFMA16(A,B,C) __builtin_amdgcn_mfma_f32_16x16x32_bf16((A),(B),(C),0,0,0)

// group a (0..11) -> w_hh row base: a0-3 pre_r, a4-7 pre_z, a8-11 gh_n
__device__ __forceinline__ int rowbase(int a){
  return (a < 4) ? a*16 : (a < 8) ? 64 + (a - 4)*16 : 128 + (a - 8)*16;
}

// one GRU step: aug fp32 VALU; h-part MFMA (hi from LDS, lo from regs)
__device__ __forceinline__ void run_step(
    const float x0[4], const float x1[4],
    const ushort_t* __restrict__ tiles, const short8 bl[24],
    const float* __restrict__ auw,
    float hc[16], short8 ahi[2], short8 alo[2], float* hb,
    int c15, int quad, int lane8)
{
  f32x4 acc[12];
  #pragma unroll
  for (int a = 0; a < 8; ++a){
    const int j = (a & 3)*16 + c15 + (a >= 4 ? 64 : 0);
    const float w0 = auw[j], w1 = auw[192 + j], bb = auw[384 + j];
    #pragma unroll
    for (int r = 0; r < 4; ++r)
      acc[a][r] = fmaf(x0[r], w0, fmaf(x1[r], w1, bb));
  }
  #pragma unroll
  for (int a = 8; a < 12; ++a){
    const float bb = auw[576 + (a - 8)*16 + c15];
    #pragma unroll
    for (int r = 0; r < 4; ++r) acc[a][r] = bb;
  }
  #pragma unroll
  for (int a = 0; a < 12; ++a){
    #pragma unroll
    for (int kt = 0; kt < 2; ++kt){
      const short8 bhi = *(const short8*)(tiles + (a*2 + kt)*512 + lane8);
      acc[a] = MFMA16(ahi[kt], bhi, acc[a]);
      acc[a] = MFMA16(alo[kt], bhi, acc[a]);
      acc[a] = MFMA16(ahi[kt], bl[a*2 + kt], acc[a]);
    }
  }
  // gates (gx_n inline fp32) + transpose via hb (stride 68)
  #pragma unroll
  for (int q = 0; q < 4; ++q){
    #pragma unroll
    for (int r = 0; r < 4; ++r){
      const float pr = acc[q][r], pz = acc[4 + q][r], gh = acc[8 + q][r];
      const int j = 128 + q*16 + c15;
      const float gx = fmaf(x0[r], auw[j], fmaf(x1[r], auw[192 + j], auw[384 + j]));
      const float rr = sigm(pr), zz = sigm(pz);
      const float nn = tanh_f(fmaf(rr, gh, gx));
      const float hn = (1.0f - zz)*nn + zz*hc[q*4 + r];
      hc[q*4 + r] = hn;
      hb[(quad*4 + r)*68 + q*16 + c15] = hn;
    }
  }
  const int m = c15, q8 = quad*8;
  #pragma unroll
  for (int kt = 0; kt < 2; ++kt){
    const f32x4* p = (const f32x4*)&hb[m*68 + kt*32 + q8];
    f32x4 a = p[0], b = p[1];
    float f[8] = {a[0], a[1], a[2], a[3], b[0], b[1], b[2], b[3]};
    #pragma unroll
    for (int j2 = 0; j2 < 8; ++j2){
      ahi[kt][j2] = (short)hib(f[j2]);
      alo[kt][j2] = (short)lob(f[j2]);
    }
  }
}

__global__ __launch_bounds__(256, 2) void rnn_mfma3(
    const float* __restrict__ X, W wp,
    const ushort_t* __restrict__ fb, float* __restrict__ out)
{
  __shared__ __align__(16) ushort_t tiles_s[28*512];   // 28 KB hi tiles (+hv/v)
  __shared__ __align__(16) float auw_s[640];
  __shared__ __align__(16) float wbuf_s[4*1744];       // per-wave hb/hv/va/lvb

  const int tid = threadIdx.x;
  const int wid = tid >> 6, lane = tid & 63;
  const int quad = lane >> 4, c15 = lane & 15;
  const int lane8 = lane*8;
  float* wl  = wbuf_s + wid*1744;
  float* hb  = wl;                 // 16*68
  float* hv  = wl + 1088;          // 16*28
  float* va  = wl + 1536;          // 16*12
  float* lvb = wl + 1728;          // 16
  const int wavebase = (blockIdx.x*4 + wid)*16;

  // ---- X row -> registers: lane holds row m=c15, elements [quad*8, quad*8+8) ----
  float xr[8];
  if (quad < 3){
    const float* xp = X + (size_t)(wavebase + c15)*24 + quad*8;
    f32x4 p0 = *(const f32x4*)xp, p1 = *(const f32x4*)(xp + 4);
    xr[0]=p0[0]; xr[1]=p0[1]; xr[2]=p0[2]; xr[3]=p0[3];
    xr[4]=p1[0]; xr[5]=p1[1]; xr[6]=p1[2]; xr[7]=p1[3];
  } else {
    #pragma unroll
    for (int i = 0; i < 8; ++i) xr[i] = 0.f;
  }
  const float lastv = X[(size_t)(wavebase + c15)*24 + 22];

  // w0[o] = sum_t query[t]*emb[t][o]; quad q holds t in [4q,4q+4) -> shfl reduce
  float w0[TOUT];
  #pragma unroll
  for (int o = 0; o < TOUT; ++o) w0[o] = 0.f;
  if (quad < 3){
    #pragma unroll
    for (int tt = 0; tt < 4; ++tt){
      const int t = quad*4 + tt;
      const float qv = xr[2*tt];
      #pragma unroll
      for (int o = 0; o < TOUT; ++o) w0[o] = fmaf(qv, wp.emb[t*TOUT + o], w0[o]);
    }
  }
  #pragma unroll
  for (int o = 0; o < TOUT; ++o){
    w0[o] += __shfl_xor(w0[o], 16, 64);
    w0[o] += __shfl_xor(w0[o], 32, 64);
  }

  // A-frags for hv GEMM (quad3 = exact-1 bias rows k=24,25)
  short8 z8 = {0,0,0,0,0,0,0,0};
  short8 axh = z8, axl = z8;
  if (quad < 3){
    #pragma unroll
    for (int j2 = 0; j2 < 8; ++j2){
      axh[j2] = (short)hib(xr[j2]);
      axl[j2] = (short)lob(xr[j2]);
    }
  } else {
    axh[0] = (short)0x3F80; axh[1] = (short)0x3F80;
  }

  float msx = -1e30f, dsum = 0.f;
  float num[TOUT];
  #pragma unroll
  for (int o = 0; o < TOUT; ++o) num[o] = 0.f;

  #pragma unroll 1
  for (int c = 0; c < CC; ++c){
    const float l1b = wp.l1b[c];

    // ======== encoder phase ========
    __syncthreads();
    {
      const float* whh = wp.ewhh + c*12288;
      for (int ch = tid; ch < 24*64; ch += 256){
        const int tile = ch >> 6, L = ch & 63;
        const int a = tile >> 1, kt = tile & 1;
        const int col = L & 15, qd = L >> 4;
        const float* src = whh + (rowbase(a) + col)*64 + kt*32 + qd*8;
        f32x4 p0 = *(const f32x4*)src, p1 = *(const f32x4*)(src + 4);
        short8 h8;
        h8[0]=(short)hib(p0[0]); h8[1]=(short)hib(p0[1]); h8[2]=(short)hib(p0[2]); h8[3]=(short)hib(p0[3]);
        h8[4]=(short)hib(p1[0]); h8[5]=(short)hib(p1[1]); h8[6]=(short)hib(p1[2]); h8[7]=(short)hib(p1[3]);
        *(short8*)(tiles_s + tile*512 + L*8) = h8;
      }
      // hv tiles (4 KB) from fb: slots 24..27 = (nt,term)
      for (int ch = tid; ch < 4*64; ch += 256){
        const int tile = ch >> 6, L = ch & 63;
        *(short8*)(tiles_s + (24 + tile)*512 + L*8) =
            *(const short8*)(fb + (size_t)(c*4 + tile)*512 + L*8);
      }
      for (int j = tid; j < 192; j += 256){
        auw_s[j]       = wp.ewih[c*384 + 2*j];
        auw_s[192 + j] = wp.ewih[c*384 + 2*j + 1];
        auw_s[384 + j] = wp.ebih[c*192 + j] + (j < 128 ? wp.ebhh[c*192 + j] : 0.f);
        if (j >= 128) auw_s[576 + (j - 128)] = wp.ebhh[c*192 + j];
      }
    }
    __syncthreads();

    // per-lane lo reg tiles (enc)
    short8 bl[24];
    {
      const float* whh = wp.ewhh + c*12288;
      #pragma unroll
      for (int t24 = 0; t24 < 24; ++t24){
        const int a = t24 >> 1, kt = t24 & 1;
        const float* src = whh + (rowbase(a) + c15)*64 + kt*32 + quad*8;
        f32x4 p0 = *(const f32x4*)src, p1 = *(const f32x4*)(src + 4);
        short8 l8;
        l8[0]=(short)lob(p0[0]); l8[1]=(short)lob(p0[1]); l8[2]=(short)lob(p0[2]); l8[3]=(short)lob(p0[3]);
        l8[4]=(short)lob(p1[0]); l8[5]=(short)lob(p1[1]); l8[6]=(short)lob(p1[2]); l8[7]=(short)lob(p1[3]);
        bl[t24] = l8;
      }
    }

    // hv GEMM: hv[m][2s+f] for all 12 encoder steps (tiles from LDS)
    #pragma unroll
    for (int nt = 0; nt < 2; ++nt){
      f32x4 a = {0.f, 0.f, 0.f, 0.f};
      const ushort_t* bp = tiles_s + (24 + nt*2)*512 + lane8;
      short8 bhi = *(const short8*)bp, blo = *(const short8*)(bp + 512);
      a = MFMA16(axh, bhi, a);
      a = MFMA16(axl, bhi, a);
      a = MFMA16(axh, blo, a);
      if (nt == 0 || c15 < 8){
        #pragma unroll
        for (int r = 0; r < 4; ++r)
          hv[(quad*4 + r)*28 + nt*16 + c15] = a[r];
      }
    }

    float hc[16];
    #pragma unroll
    for (int q = 0; q < 16; ++q) hc[q] = 0.f;
    short8 ahi[2], alo[2];
    ahi[0] = z8; ahi[1] = z8; alo[0] = z8; alo[1] = z8;

    const int steps = 3 + c;
    #pragma unroll 1
    for (int j = 0; j < steps; ++j){
      float x0[4], x1[4];
      #pragma unroll
      for (int r = 0; r < 4; ++r){
        x0[r] = hv[(quad*4 + r)*28 + 2*j];
        x1[r] = hv[(quad*4 + r)*28 + 2*j + 1];
      }
      run_step(x0, x1, tiles_s, bl, auw_s, hc, ahi, alo, hb, c15, quad, lane8);
    }

    // ======== decoder phase ========
    __syncthreads();
    {
      const float* whh = wp.dwhh + c*12288;
      for (int ch = tid; ch < 24*64; ch += 256){
        const int tile = ch >> 6, L = ch & 63;
        const int a = tile >> 1, kt = tile & 1;
        const int col = L & 15, qd = L >> 4;
        const float* src = whh + (rowbase(a) + col)*64 + kt*32 + qd*8;
        f32x4 p0 = *(const f32x4*)src, p1 = *(const f32x4*)(src + 4);
        short8 h8;
        h8[0]=(short)hib(p0[0]); h8[1]=(short)hib(p0[1]); h8[2]=(short)hib(p0[2]); h8[3]=(short)hib(p0[3]);
        h8[4]=(short)hib(p1[0]); h8[5]=(short)hib(p1[1]); h8[6]=(short)hib(p1[2]); h8[7]=(short)hib(p1[3]);
        *(short8*)(tiles_s + tile*512 + L*8) = h8;
      }
      // v hi tiles (l1w in col 0): slots 24..25
      for (int ch = tid; ch < 2*64; ch += 256){
        const int tile = ch >> 6, L = ch & 63;
        const int col = L & 15, qd = L >> 4;
        short8 v8 = {0,0,0,0,0,0,0,0};
        if (col == 0){
          const float* src = wp.l1w + c*64 + tile*32 + qd*8;
          f32x4 p0 = *(const f32x4*)src, p1 = *(const f32x4*)(src + 4);
          v8[0]=(short)hib(p0[0]); v8[1]=(short)hib(p0[1]); v8[2]=(short)hib(p0[2]); v8[3]=(short)hib(p0[3]);
          v8[4]=(short)hib(p1[0]); v8[5]=(short)hib(p1[1]); v8[6]=(short)hib(p1[2]); v8[7]=(short)hib(p1[3]);
        }
        *(short8*)(tiles_s + (24 + tile)*512 + L*8) = v8;
      }
      for (int j = tid; j < 192; j += 256){
        auw_s[j]       = wp.dwih[c*192 + j];
        auw_s[192 + j] = 0.f;
        auw_s[384 + j] = wp.dbih[c*192 + j] + (j < 128 ? wp.dbhh[c*192 + j] : 0.f);
        if (j >= 128) auw_s[576 + (j - 128)] = wp.dbhh[c*192 + j];
      }
    }
    __syncthreads();

    // per-lane lo reg tiles (dec) + v lo tiles
    short8 blv[2];
    {
      const float* whh = wp.dwhh + c*12288;
      #pragma unroll
      for (int t24 = 0; t24 < 24; ++t24){
        const int a = t24 >> 1, kt = t24 & 1;
        const float* src = whh + (rowbase(a) + c15)*64 + kt*32 + quad*8;
        f32x4 p0 = *(const f32x4*)src, p1 = *(const f32x4*)(src + 4);
        short8 l8;
        l8[0]=(short)lob(p0[0]); l8[1]=(short)lob(p0[1]); l8[2]=(short)lob(p0[2]); l8[3]=(short)lob(p0[3]);
        l8[4]=(short)lob(p1[0]); l8[5]=(short)lob(p1[1]); l8[6]=(short)lob(p1[2]); l8[7]=(short)lob(p1[3]);
        bl[t24] = l8;
      }
      #pragma unroll
      for (int kt = 0; kt < 2; ++kt){
        short8 l8 = z8;
        if (c15 == 0){
          const float* src = wp.l1w + c*64 + kt*32 + quad*8;
          f32x4 p0 = *(const f32x4*)src, p1 = *(const f32x4*)(src + 4);
          l8[0]=(short)lob(p0[0]); l8[1]=(short)lob(p0[1]); l8[2]=(short)lob(p0[2]); l8[3]=(short)lob(p0[3]);
          l8[4]=(short)lob(p1[0]); l8[5]=(short)lob(p1[1]); l8[6]=(short)lob(p1[2]); l8[7]=(short)lob(p1[3]);
        }
        blv[kt] = l8;
      }
    }

    if (quad == 0) lvb[c15] = lastv;

    const float zx1[4] = {0.f, 0.f, 0.f, 0.f};
    #pragma unroll 1
    for (int i = 0; i < TOUT; ++i){
      if (i > 0){
        f32x4 accv = {l1b, l1b, l1b, l1b};
        #pragma unroll
        for (int kt = 0; kt < 2; ++kt){
          const short8 bhi = *(const short8*)(tiles_s + (24 + kt)*512 + lane8);
          accv = MFMA16(ahi[kt], bhi, accv);
          accv = MFMA16(alo[kt], bhi, accv);
          accv = MFMA16(ahi[kt], blv[kt], accv);
        }
        if (c15 == 0){
          #pragma unroll
          for (int r = 0; r < 4; ++r){
            va[(quad*4 + r)*12 + (i - 1)] = accv[r];
            lvb[quad*4 + r] = accv[r];
          }
        }
      }
      float x0[4];
      #pragma unroll
      for (int r = 0; r < 4; ++r) x0[r] = lvb[quad*4 + r];
      run_step(x0, zx1, tiles_s, bl, auw_s, hc, ahi, alo, hb, c15, quad, lane8);
    }
    {
      f32x4 accv = {l1b, l1b, l1b, l1b};
      #pragma unroll
      for (int kt = 0; kt < 2; ++kt){
        const short8 bhi = *(const short8*)(tiles_s + (24 + kt)*512 + lane8);
        accv = MFMA16(ahi[kt], bhi, accv);
        accv = MFMA16(alo[kt], bhi, accv);
        accv = MFMA16(ahi[kt], blv[kt], accv);
      }
      if (c15 == 0){
        #pragma unroll
        for (int r = 0; r < 4; ++r) va[(quad*4 + r)*12 + 11] = accv[r];
      }
    }

    // online softmax update (per-lane, m=c15)
    {
      float l = 0.f;
      #pragma unroll
      for (int o = 0; o < TOUT; ++o) l = fmaf(w0[o], va[c15*12 + o], l);
      const float nmx = fmaxf(msx, l);
      const float aa = __expf(msx - nmx);
      const float ee = __expf(l - nmx);
      dsum = dsum*aa + ee;
      #pragma unroll
      for (int o = 0; o < TOUT; ++o) num[o] = num[o]*aa + va[c15*12 + o]*ee;
      msx = nmx;
    }
  }

  if (quad == 0){
    const float inv = 1.0f / dsum;
    #pragma unroll
    for (int o = 0; o < TOUT; ++o)
      out[(size_t)(wavebase + c15)*12 + o] = num[o]*inv;
  }
}

extern "C" void kernel_launch(void* const* d_in, const int* in_sizes, int n_in,
                              void* d_out, int out_size, void* d_ws, size_t ws_size,
                              hipStream_t stream) {
  int iX = 1, iW = 2;
  for (int i = 0; i < n_in; ++i){
    if (in_sizes[i] == 3145728) iX = i;
    if (in_sizes[i] == 3840)   { iW = i; break; }
  }
  W wp;
  wp.ewih = (const float*)d_in[iW + 0];
  wp.ewhh = (const float*)d_in[iW + 1];
  wp.ebih = (const float*)d_in[iW + 2];
  wp.ebhh = (const float*)d_in[iW + 3];
  wp.dwih = (const float*)d_in[iW + 4];
  wp.dwhh = (const float*)d_in[iW + 5];
  wp.dbih = (const float*)d_in[iW + 6];
  wp.dbhh = (const float*)d_in[iW + 7];
  wp.l1w  = (const float*)d_in[iW + 8];
  wp.l1b  = (const float*)d_in[iW + 9];
  wp.l2w  = (const float*)d_in[iW + 10];
  wp.l2b  = (const float*)d_in[iW + 11];
  wp.emb  = (const float*)d_in[iW + 12];

  ushort_t* fb = (ushort_t*)d_ws;   // only 40 KB of enc-hv tiles now

  prep_hv<<<40, 256, 0, stream>>>(wp, fb);
  rnn_mfma3<<<BNTOT / 64, 256, 0, stream>>>(
      (const float*)d_in[iX], wp, fb, (float*)d_out);
}

// Round 8
// 3120.516 us; speedup vs baseline: 4.1578x; 4.1578x over previous
//
#include <hip/hip_runtime.h>

typedef __attribute__((ext_vector_type(8))) _Float16 half8;
typedef __attribute__((ext_vector_type(4))) float f32x4;

#define HH 64
#define TT 12
#define TOUT 12
#define CC 10
#define BNTOT 131072

__device__ __forceinline__ float sigm(float x){
  return __builtin_amdgcn_rcpf(1.0f + __expf(-x));
}
__device__ __forceinline__ float tanh_f(float x){
  return 1.0f - 2.0f * __builtin_amdgcn_rcpf(1.0f + __expf(2.0f * x));
}

struct W {
  const float* ewih; const float* ewhh; const float* ebih; const float* ebhh;
  const float* dwih; const float* dwhh; const float* dbih; const float* dbhh;
  const float* l1w;  const float* l1b;  const float* l2w;  const float* l2b;
  const float* emb;
};

#define MFMAH(A,B,C) __builtin_amdgcn_mfma_f32_16x16x32_f16((A),(B),(C),0,0,0)

// group a (0..11) -> w_hh row base: a0-3 pre_r, a4-7 pre_z, a8-11 gh_n
__device__ __forceinline__ int rowbase(int a){
  return (a < 4) ? a*16 : (a < 8) ? 64 + (a - 4)*16 : 128 + (a - 8)*16;
}

// One GRU step. aug path fp32 VALU (exact); h-part single fp16 MFMA per (a,kt).
// All per-step operands come from LDS (24 KB shared tiles) or registers.
__device__ __forceinline__ void run_step(
    const float x0[4], const float x1[4],
    const _Float16* __restrict__ tiles,
    const float aw0[8], const float aw1[8], const float ab[8],
    const float ghb[4], const float gxw0[4], const float gxw1[4], const float gxb[4],
    float hc[16], half8 ahi[2], float* hb,
    int c15, int quad, int lane8)
{
  f32x4 acc[12];
  #pragma unroll
  for (int a = 0; a < 8; ++a){
    #pragma unroll
    for (int r = 0; r < 4; ++r)
      acc[a][r] = fmaf(x0[r], aw0[a], fmaf(x1[r], aw1[a], ab[a]));
  }
  #pragma unroll
  for (int q = 0; q < 4; ++q){
    #pragma unroll
    for (int r = 0; r < 4; ++r) acc[8 + q][r] = ghb[q];
  }
  #pragma unroll
  for (int a = 0; a < 12; ++a){
    #pragma unroll
    for (int kt = 0; kt < 2; ++kt){
      const half8 bh = *(const half8*)(tiles + (a*2 + kt)*512 + lane8);
      acc[a] = MFMAH(ahi[kt], bh, acc[a]);
    }
  }
  // gates (gx_n inline fp32) + transpose via hb (stride 68, 16B-aligned rows)
  #pragma unroll
  for (int q = 0; q < 4; ++q){
    #pragma unroll
    for (int r = 0; r < 4; ++r){
      const float pr = acc[q][r], pz = acc[4 + q][r], gh = acc[8 + q][r];
      const float gx = fmaf(x0[r], gxw0[q], fmaf(x1[r], gxw1[q], gxb[q]));
      const float rr = sigm(pr), zz = sigm(pz);
      const float nn = tanh_f(fmaf(rr, gh, gx));
      const float hn = (1.0f - zz)*nn + zz*hc[q*4 + r];
      hc[q*4 + r] = hn;
      hb[(quad*4 + r)*68 + q*16 + c15] = hn;
    }
  }
  const int m = c15, q8 = quad*8;
  #pragma unroll
  for (int kt = 0; kt < 2; ++kt){
    const f32x4* p = (const f32x4*)&hb[m*68 + kt*32 + q8];
    f32x4 a = p[0], b = p[1];
    half8 h;
    h[0]=(_Float16)a[0]; h[1]=(_Float16)a[1]; h[2]=(_Float16)a[2]; h[3]=(_Float16)a[3];
    h[4]=(_Float16)b[0]; h[5]=(_Float16)b[1]; h[6]=(_Float16)b[2]; h[7]=(_Float16)b[3];
    ahi[kt] = h;
  }
}

__global__ __launch_bounds__(256, 2) void rnn_mfma4(
    const float* __restrict__ X, W wp, float* __restrict__ out)
{
  __shared__ __align__(16) _Float16 tiles_s[26*512];   // 24 whh tiles + 2 hv/v
  __shared__ __align__(16) float wbuf_s[4*1744];       // per-wave hb/hv/va/lvb

  const int tid = threadIdx.x;
  const int wid = tid >> 6, lane = tid & 63;
  const int quad = lane >> 4, c15 = lane & 15;
  const int lane8 = lane*8;
  float* wl  = wbuf_s + wid*1744;
  float* hb  = wl;                 // 16*68
  float* hv  = wl + 1088;          // 16*28
  float* va  = wl + 1536;          // 16*12
  float* lvb = wl + 1728;          // 16
  const int wavebase = (blockIdx.x*4 + wid)*16;

  // ---- X row -> regs: lane holds sample m=c15, elements [quad*8, quad*8+8) ----
  float xr[8];
  if (quad < 3){
    const float* xp = X + (size_t)(wavebase + c15)*24 + quad*8;
    f32x4 p0 = *(const f32x4*)xp, p1 = *(const f32x4*)(xp + 4);
    xr[0]=p0[0]; xr[1]=p0[1]; xr[2]=p0[2]; xr[3]=p0[3];
    xr[4]=p1[0]; xr[5]=p1[1]; xr[6]=p1[2]; xr[7]=p1[3];
  } else {
    #pragma unroll
    for (int i = 0; i < 8; ++i) xr[i] = 0.f;
  }
  const float lastv = X[(size_t)(wavebase + c15)*24 + 22];

  // w0[o] = sum_t query[t]*emb[t][o]; quad q holds t in [4q,4q+4) -> shfl reduce
  float w0[TOUT];
  #pragma unroll
  for (int o = 0; o < TOUT; ++o) w0[o] = 0.f;
  if (quad < 3){
    #pragma unroll
    for (int tt = 0; tt < 4; ++tt){
      const int t = quad*4 + tt;
      const float qv = xr[2*tt];
      #pragma unroll
      for (int o = 0; o < TOUT; ++o) w0[o] = fmaf(qv, wp.emb[t*TOUT + o], w0[o]);
    }
  }
  #pragma unroll
  for (int o = 0; o < TOUT; ++o){
    w0[o] += __shfl_xor(w0[o], 16, 64);
    w0[o] += __shfl_xor(w0[o], 32, 64);
  }

  // A-frag for hv GEMM (quad3 = exact-1.0 bias row k=24)
  half8 axh = {0,0,0,0,0,0,0,0};
  if (quad < 3){
    #pragma unroll
    for (int j2 = 0; j2 < 8; ++j2) axh[j2] = (_Float16)xr[j2];
  } else {
    axh[0] = (_Float16)1.0f;
  }

  float msx = -1e30f, dsum = 0.f;
  float num[TOUT];
  #pragma unroll
  for (int o = 0; o < TOUT; ++o) num[o] = 0.f;

  #pragma unroll 1
  for (int c = 0; c < CC; ++c){
    const float l1b = wp.l1b[c];

    // ======== encoder phase ========
    __syncthreads();
    {
      const float* whh = wp.ewhh + c*12288;
      for (int ch = tid; ch < 24*64; ch += 256){
        const int tile = ch >> 6, L = ch & 63;
        const int a = tile >> 1, kt = tile & 1;
        const int col = L & 15, qd = L >> 4;
        const float* src = whh + (rowbase(a) + col)*64 + kt*32 + qd*8;
        f32x4 p0 = *(const f32x4*)src, p1 = *(const f32x4*)(src + 4);
        half8 h;
        h[0]=(_Float16)p0[0]; h[1]=(_Float16)p0[1]; h[2]=(_Float16)p0[2]; h[3]=(_Float16)p0[3];
        h[4]=(_Float16)p1[0]; h[5]=(_Float16)p1[1]; h[6]=(_Float16)p1[2]; h[7]=(_Float16)p1[3];
        *(half8*)(tiles_s + tile*512 + L*8) = h;
      }
      // hv tiles from l2w/l2b: slot 24+nt; B[k=2t+f2][col] = (f2==f)*w2[j][t], row24=b2[j]
      for (int ch = tid; ch < 2*64; ch += 256){
        const int nt = ch >> 6, L = ch & 63;
        const int col = L & 15, qd = L >> 4;
        const int j_ = nt*8 + (col >> 1), f_ = col & 1;
        const bool okc = (nt == 0) || (col < 8);
        half8 h;
        #pragma unroll
        for (int jj = 0; jj < 8; ++jj){
          const int k = qd*8 + jj;
          float v = 0.f;
          if (okc){
            if (k < 24){
              const int t = k >> 1, f2 = k & 1;
              if (f2 == f_) v = wp.l2w[c*144 + j_*12 + t];
            } else if (k == 24){
              v = wp.l2b[c*12 + j_];
            }
          }
          h[jj] = (_Float16)v;
        }
        *(half8*)(tiles_s + (24 + nt)*512 + L*8) = h;
      }
    }
    __syncthreads();

    // enc aug regs (per-lane, statically indexed -> real VGPRs)
    float aw0[8], aw1[8], ab[8], ghb[4], gxw0[4], gxw1[4], gxb[4];
    #pragma unroll
    for (int a = 0; a < 8; ++a){
      const int j = (a & 3)*16 + c15 + (a >= 4 ? 64 : 0);
      aw0[a] = wp.ewih[c*384 + 2*j];
      aw1[a] = wp.ewih[c*384 + 2*j + 1];
      ab[a]  = wp.ebih[c*192 + j] + wp.ebhh[c*192 + j];
    }
    #pragma unroll
    for (int q = 0; q < 4; ++q){
      const int j = 128 + q*16 + c15;
      ghb[q]  = wp.ebhh[c*192 + j];
      gxw0[q] = wp.ewih[c*384 + 2*j];
      gxw1[q] = wp.ewih[c*384 + 2*j + 1];
      gxb[q]  = wp.ebih[c*192 + j];
    }

    // hv GEMM: inputs for all 12 encoder steps
    #pragma unroll
    for (int nt = 0; nt < 2; ++nt){
      f32x4 a = {0.f, 0.f, 0.f, 0.f};
      const half8 bh = *(const half8*)(tiles_s + (24 + nt)*512 + lane8);
      a = MFMAH(axh, bh, a);
      if (nt == 0 || c15 < 8){
        #pragma unroll
        for (int r = 0; r < 4; ++r)
          hv[(quad*4 + r)*28 + nt*16 + c15] = a[r];
      }
    }

    float hc[16];
    #pragma unroll
    for (int q = 0; q < 16; ++q) hc[q] = 0.f;
    half8 ahi[2];
    ahi[0] = (half8){0,0,0,0,0,0,0,0};
    ahi[1] = (half8){0,0,0,0,0,0,0,0};

    const int steps = 3 + c;
    #pragma unroll 1
    for (int j = 0; j < steps; ++j){
      float x0[4], x1[4];
      #pragma unroll
      for (int r = 0; r < 4; ++r){
        const float2 p = *(const float2*)&hv[(quad*4 + r)*28 + 2*j];
        x0[r] = p.x; x1[r] = p.y;
      }
      run_step(x0, x1, tiles_s, aw0, aw1, ab, ghb, gxw0, gxw1, gxb,
               hc, ahi, hb, c15, quad, lane8);
    }

    // ======== decoder phase ========
    __syncthreads();
    {
      const float* whh = wp.dwhh + c*12288;
      for (int ch = tid; ch < 24*64; ch += 256){
        const int tile = ch >> 6, L = ch & 63;
        const int a = tile >> 1, kt = tile & 1;
        const int col = L & 15, qd = L >> 4;
        const float* src = whh + (rowbase(a) + col)*64 + kt*32 + qd*8;
        f32x4 p0 = *(const f32x4*)src, p1 = *(const f32x4*)(src + 4);
        half8 h;
        h[0]=(_Float16)p0[0]; h[1]=(_Float16)p0[1]; h[2]=(_Float16)p0[2]; h[3]=(_Float16)p0[3];
        h[4]=(_Float16)p1[0]; h[5]=(_Float16)p1[1]; h[6]=(_Float16)p1[2]; h[7]=(_Float16)p1[3];
        *(half8*)(tiles_s + tile*512 + L*8) = h;
      }
      // v tiles (l1w in col 0): slots 24..25
      for (int ch = tid; ch < 2*64; ch += 256){
        const int kt = ch >> 6, L = ch & 63;
        const int col = L & 15, qd = L >> 4;
        half8 h = {0,0,0,0,0,0,0,0};
        if (col == 0){
          const float* src = wp.l1w + c*64 + kt*32 + qd*8;
          f32x4 p0 = *(const f32x4*)src, p1 = *(const f32x4*)(src + 4);
          h[0]=(_Float16)p0[0]; h[1]=(_Float16)p0[1]; h[2]=(_Float16)p0[2]; h[3]=(_Float16)p0[3];
          h[4]=(_Float16)p1[0]; h[5]=(_Float16)p1[1]; h[6]=(_Float16)p1[2]; h[7]=(_Float16)p1[3];
        }
        *(half8*)(tiles_s + (24 + kt)*512 + L*8) = h;
      }
    }
    __syncthreads();

    // dec aug regs
    #pragma unroll
    for (int a = 0; a < 8; ++a){
      const int j = (a & 3)*16 + c15 + (a >= 4 ? 64 : 0);
      aw0[a] = wp.dwih[c*192 + j];
      aw1[a] = 0.f;
      ab[a]  = wp.dbih[c*192 + j] + wp.dbhh[c*192 + j];
    }
    #pragma unroll
    for (int q = 0; q < 4; ++q){
      const int j = 128 + q*16 + c15;
      ghb[q]  = wp.dbhh[c*192 + j];
      gxw0[q] = wp.dwih[c*192 + j];
      gxw1[q] = 0.f;
      gxb[q]  = wp.dbih[c*192 + j];
    }

    if (quad == 0) lvb[c15] = lastv;

    const float zx1[4] = {0.f, 0.f, 0.f, 0.f};
    #pragma unroll 1
    for (int i = 0; i < TOUT; ++i){
      if (i > 0){
        f32x4 accv = {l1b, l1b, l1b, l1b};
        #pragma unroll
        for (int kt = 0; kt < 2; ++kt){
          const half8 bh = *(const half8*)(tiles_s + (24 + kt)*512 + lane8);
          accv = MFMAH(ahi[kt], bh, accv);
        }
        if (c15 == 0){
          #pragma unroll
          for (int r = 0; r < 4; ++r){
            va[(quad*4 + r)*12 + (i - 1)] = accv[r];
            lvb[quad*4 + r] = accv[r];
          }
        }
      }
      float x0[4];
      #pragma unroll
      for (int r = 0; r < 4; ++r) x0[r] = lvb[quad*4 + r];
      run_step(x0, zx1, tiles_s, aw0, aw1, ab, ghb, gxw0, gxw1, gxb,
               hc, ahi, hb, c15, quad, lane8);
    }
    {
      f32x4 accv = {l1b, l1b, l1b, l1b};
      #pragma unroll
      for (int kt = 0; kt < 2; ++kt){
        const half8 bh = *(const half8*)(tiles_s + (24 + kt)*512 + lane8);
        accv = MFMAH(ahi[kt], bh, accv);
      }
      if (c15 == 0){
        #pragma unroll
        for (int r = 0; r < 4; ++r) va[(quad*4 + r)*12 + 11] = accv[r];
      }
    }

    // online softmax update (per-lane, m=c15)
    {
      float l = 0.f;
      #pragma unroll
      for (int o = 0; o < TOUT; ++o) l = fmaf(w0[o], va[c15*12 + o], l);
      const float nmx = fmaxf(msx, l);
      const float aa = __expf(msx - nmx);
      const float ee = __expf(l - nmx);
      dsum = dsum*aa + ee;
      #pragma unroll
      for (int o = 0; o < TOUT; ++o) num[o] = num[o]*aa + va[c15*12 + o]*ee;
      msx = nmx;
    }
  }

  if (quad == 0){
    const float inv = 1.0f / dsum;
    #pragma unroll
    for (int o = 0; o < TOUT; ++o)
      out[(size_t)(wavebase + c15)*12 + o] = num[o]*inv;
  }
}

extern "C" void kernel_launch(void* const* d_in, const int* in_sizes, int n_in,
                              void* d_out, int out_size, void* d_ws, size_t ws_size,
                              hipStream_t stream) {
  int iX = 1, iW = 2;
  for (int i = 0; i < n_in; ++i){
    if (in_sizes[i] == 3145728) iX = i;
    if (in_sizes[i] == 3840)   { iW = i; break; }
  }
  W wp;
  wp.ewih = (const float*)d_in[iW + 0];
  wp.ewhh = (const float*)d_in[iW + 1];
  wp.ebih = (const float*)d_in[iW + 2];
  wp.ebhh = (const float*)d_in[iW + 3];
  wp.dwih = (const float*)d_in[iW + 4];
  wp.dwhh = (const float*)d_in[iW + 5];
  wp.dbih = (const float*)d_in[iW + 6];
  wp.dbhh = (const float*)d_in[iW + 7];
  wp.l1w  = (const float*)d_in[iW + 8];
  wp.l1b  = (const float*)d_in[iW + 9];
  wp.l2w  = (const float*)d_in[iW + 10];
  wp.l2b  = (const float*)d_in[iW + 11];
  wp.emb  = (const float*)d_in[iW + 12];

  rnn_mfma4<<<BNTOT / 64, 256, 0, stream>>>(
      (const float*)d_in[iX], wp, (float*)d_out);
}